// Round 3
// baseline (189.253 us; speedup 1.0000x reference)
//
#include <hip/hip_runtime.h>

#define BATCH 256
#define TT 256
#define DD 384
#define HH 64
#define SCALE 0.125f
#define SHIFT 14.0f

typedef __attribute__((ext_vector_type(8))) short short8;
typedef __attribute__((ext_vector_type(4))) float floatx4;

#define WELEMS (3 * DD * HH)      // 73,728 bf16 = 147,456 B packed W
#define WCHUNK (12 * 512)         // 6,144 bf16 = 12 KB per K-chunk of packed W
#define PS_STRIDE 40              // per-wave P scratch [16][40] bf16

// workspace layout (bytes)
#define WF_OFF 0
#define Q_OFF  147456
#define K_OFF  (Q_OFF + BATCH * TT * HH * 2)     // +8,388,608
#define VT_OFF (K_OFF + BATCH * TT * HH * 2)     // +8,388,608  (total ~25.3 MB)

__device__ __forceinline__ unsigned short f2bf(float f) {
    unsigned int u = __float_as_uint(f);
    u += 0x7fffu + ((u >> 16) & 1u);
    return (unsigned short)(u >> 16);
}
__device__ __forceinline__ float bf2f(unsigned short u) {
    return __uint_as_float(((unsigned int)u) << 16);
}

// async 16B global->LDS DMA; lane i lands at ldst + i*16B (ldst wave-uniform).
__device__ __forceinline__ void gld_lds16(const void* g, void* ldst) {
    __builtin_amdgcn_global_load_lds(
        (__attribute__((address_space(1))) void*)(unsigned long long)g,
        (__attribute__((address_space(3))) void*)(unsigned int)(unsigned long long)ldst,
        16, 0, 0);
}

// 8 fp32 -> bf16 A-fragment
__device__ __forceinline__ short8 cvt8(float4 f0, float4 f1) {
    short8 a;
    a[0] = (short)f2bf(f0.x); a[1] = (short)f2bf(f0.y);
    a[2] = (short)f2bf(f0.z); a[3] = (short)f2bf(f0.w);
    a[4] = (short)f2bf(f1.x); a[5] = (short)f2bf(f1.y);
    a[6] = (short)f2bf(f1.z); a[7] = (short)f2bf(f1.w);
    return a;
}

// Pack W fp32 [D][H] -> fragment-major bf16: wf[((ch*3+mat)*4+nt)*512 + lane*8 + j]
// holds W[d = 32ch + 8*(lane>>4) + j][h = 16nt + (lane&15)].
__global__ void pack_w_kernel(const float* __restrict__ wq,
                              const float* __restrict__ wk,
                              const float* __restrict__ wv,
                              unsigned short* __restrict__ wf) {
    int idx = blockIdx.x * 256 + threadIdx.x;
    if (idx >= WELEMS) return;
    int j = idx & 7;
    int lane = (idx >> 3) & 63;
    int nt = (idx >> 9) & 3;
    int rem = idx >> 11;                   // ch*3 + mat
    int mat = rem % 3;
    int ch = rem / 3;
    int l16 = lane & 15, q = lane >> 4;
    int h = 16 * nt + l16;
    int d = 32 * ch + 8 * q + j;
    const float* w = (mat == 0) ? wq : (mat == 1) ? wk : wv;
    wf[idx] = f2bf(w[d * HH + h]);
}

// ---------------- QKV GEMM: 1024 blocks x 256 thr (4 waves, 16 rows/wave) ------
// Block B: batch b = B & 255 (XCD-colocated sub-blocks), quarter qb = B >> 8
// covering rows [64*qb, 64*qb+64). W streamed chunk-by-chunk through a 2x12KB
// LDS double buffer (one barrier per chunk; ~3 blocks/CU decouple the stalls).
// Outputs bf16: Q,K row-major [T][H]; Vt transposed [H][T].
__global__ __launch_bounds__(256)
void qkv_kernel(const float* __restrict__ x, const unsigned short* __restrict__ wf,
                unsigned short* __restrict__ wsq, unsigned short* __restrict__ wsk,
                unsigned short* __restrict__ wsv) {
    __shared__ __align__(16) unsigned short Wbuf[2][WCHUNK];   // 24,576 B

    const int B = blockIdx.x;
    const int b = B & 255, qb = B >> 8;
    const int tid = threadIdx.x;
    const int wave = tid >> 6;
    const int lane = tid & 63;
    const int quad = lane >> 4;
    const int l16 = lane & 15;
    const int base = 64 * qb + 16 * wave;          // row base within batch

    const float* xr = x + ((size_t)b * TT + base + l16) * DD + 8 * quad;

    floatx4 cq[4] = {}, ck[4] = {}, cv[4] = {};
    float4 xA0, xA1, xB0, xB1;
    xA0 = *(const float4*)(xr);       xA1 = *(const float4*)(xr + 4);
    xB0 = *(const float4*)(xr + 32);  xB1 = *(const float4*)(xr + 36);

    // stage chunk 0 (768 x 16B granules, 3 per thread, linear layout)
    #pragma unroll
    for (int i = 0; i < 3; ++i)
        gld_lds16(wf + (size_t)(256 * i + wave * 64 + lane) * 8,
                  &Wbuf[0][(256 * i + wave * 64) * 8]);

    #define QKV_BODY(X0, X1, CH)                                                    \
        {                                                                           \
            __syncthreads();  /* chunk CH landed; prior buffer reads done */        \
            if ((CH) + 1 < 12) {                                                    \
                _Pragma("unroll")                                                   \
                for (int i = 0; i < 3; ++i)                                         \
                    gld_lds16(wf + (size_t)((CH) + 1) * WCHUNK                      \
                                 + (size_t)(256 * i + wave * 64 + lane) * 8,        \
                              &Wbuf[((CH) + 1) & 1][(256 * i + wave * 64) * 8]);    \
            }                                                                       \
            short8 a0 = cvt8(X0, X1);                                               \
            if ((CH) + 2 < 12) {                                                    \
                X0 = *(const float4*)(xr + ((CH) + 2) * 32);                        \
                X1 = *(const float4*)(xr + ((CH) + 2) * 32 + 4);                    \
            }                                                                       \
            const unsigned short* wb = Wbuf[(CH) & 1];                              \
            _Pragma("unroll")                                                       \
            for (int nt = 0; nt < 4; ++nt) {                                        \
                short8 w0 = *(const short8*)(wb + (nt) * 512 + lane * 8);           \
                short8 w1 = *(const short8*)(wb + (4 + nt) * 512 + lane * 8);       \
                short8 w2 = *(const short8*)(wb + (8 + nt) * 512 + lane * 8);       \
                cq[nt] = __builtin_amdgcn_mfma_f32_16x16x32_bf16(a0, w0, cq[nt], 0, 0, 0); \
                ck[nt] = __builtin_amdgcn_mfma_f32_16x16x32_bf16(a0, w1, ck[nt], 0, 0, 0); \
                cv[nt] = __builtin_amdgcn_mfma_f32_16x16x32_bf16(a0, w2, cv[nt], 0, 0, 0); \
            }                                                                       \
        }

    #pragma unroll 1
    for (int t = 0; t < 6; ++t) {
        QKV_BODY(xA0, xA1, 2 * t);
        QKV_BODY(xB0, xB1, 2 * t + 1);
    }
    #undef QKV_BODY

    // Epilogue: C row = base + 4*quad + r, col = 16*nt + l16
    unsigned short* qw = wsq + ((size_t)b * TT + base) * HH;
    unsigned short* kw = wsk + ((size_t)b * TT + base) * HH;
    unsigned short* vw = wsv + (size_t)b * HH * TT;
    #pragma unroll
    for (int nt = 0; nt < 4; ++nt)
      #pragma unroll
      for (int r = 0; r < 4; ++r) {
        int rr = 4 * quad + r;
        qw[(size_t)rr * HH + 16 * nt + l16] = f2bf(cq[nt][r]);
        kw[(size_t)rr * HH + 16 * nt + l16] = f2bf(ck[nt][r]);
        vw[(size_t)(16 * nt + l16) * TT + base + rr] = f2bf(cv[nt][r]);
      }
}

// ---------------- Attention: 1024 blocks x 256 thr, ONE q-group per wave -------
// Block B: batch b = B & 255, j = B >> 8; wave w handles group g = j + 4w
// (rows [16g,16g+16)). Q/K/Vt B-fragments read straight from global (L2-resident,
// 16B/lane coalesced); only P scratch in LDS (5 KB) -> ~16 waves/CU.
__global__ __launch_bounds__(256)
void attn_kernel(const unsigned short* __restrict__ wsq,
                 const unsigned short* __restrict__ wsk,
                 const unsigned short* __restrict__ wsv,
                 float* __restrict__ out) {
    __shared__ __align__(16) unsigned short P[4][16 * PS_STRIDE];   // 5,120 B

    const int B = blockIdx.x;
    const int b = B & 255, j = B >> 8;
    const int tid = threadIdx.x;
    const int wave = tid >> 6;
    const int lane = tid & 63;
    const int quad = lane >> 4;
    const int l16 = lane & 15;
    const int g = j + 4 * wave;        // 0..15
    const int gr0 = 16 * g;

    const unsigned short* Qb = wsq + (size_t)b * TT * HH;
    const unsigned short* Kb = wsk + (size_t)b * TT * HH;
    const unsigned short* Vb = wsv + (size_t)b * HH * TT;

    short8 aq0 = *(const short8*)(Qb + (size_t)(gr0 + l16) * HH + 8 * quad);
    short8 aq1 = *(const short8*)(Qb + (size_t)(gr0 + l16) * HH + 32 + 8 * quad);

    floatx4 o[4] = {};
    float l_run[4] = {0.f, 0.f, 0.f, 0.f};
    unsigned short* psw = P[wave];
    const int clast = g >> 1;

    for (int c = 0; c <= clast; ++c) {
        floatx4 s[2] = {};
        #pragma unroll
        for (int ni = 0; ni < 2; ++ni) {
            const unsigned short* kp = Kb + (size_t)(32 * c + 16 * ni + l16) * HH + 8 * quad;
            s[ni] = __builtin_amdgcn_mfma_f32_16x16x32_bf16(aq0, *(const short8*)(kp), s[ni], 0, 0, 0);
            s[ni] = __builtin_amdgcn_mfma_f32_16x16x32_bf16(aq1, *(const short8*)(kp + 32), s[ni], 0, 0, 0);
        }
        bool partial = (c == clast);
        #pragma unroll
        for (int r = 0; r < 4; ++r) {
            int row = gr0 + 4 * quad + r;
            float p0 = __expf(s[0][r] * SCALE - SHIFT);
            float p1 = __expf(s[1][r] * SCALE - SHIFT);
            if (partial) {
                if (32 * c + l16 > row) p0 = 0.f;
                if (32 * c + 16 + l16 > row) p1 = 0.f;
            }
            unsigned short b0 = f2bf(p0), b1 = f2bf(p1);
            l_run[r] += bf2f(b0) + bf2f(b1);    // consistent with bf16 P fed to PV
            psw[(4 * quad + r) * PS_STRIDE + l16] = b0;
            psw[(4 * quad + r) * PS_STRIDE + 16 + l16] = b1;
        }
        short8 ap = *(const short8*)(psw + l16 * PS_STRIDE + quad * 8);
        #pragma unroll
        for (int nt = 0; nt < 4; ++nt) {
            short8 bv = *(const short8*)(Vb + (size_t)(16 * nt + l16) * TT + 32 * c + quad * 8);
            o[nt] = __builtin_amdgcn_mfma_f32_16x16x32_bf16(ap, bv, o[nt], 0, 0, 0);
        }
    }

    // Epilogue: l-reduce across the 16 lanes of each row, one reciprocal, store.
    float* outb = out + (size_t)b * TT * HH;
    float linv[4];
    #pragma unroll
    for (int r = 0; r < 4; ++r) {
        float l = l_run[r];
        l += __shfl_xor(l, 1);
        l += __shfl_xor(l, 2);
        l += __shfl_xor(l, 4);
        l += __shfl_xor(l, 8);
        linv[r] = 1.0f / l;
    }
    #pragma unroll
    for (int nt = 0; nt < 4; ++nt)
      #pragma unroll
      for (int r = 0; r < 4; ++r) {
        int row = gr0 + 4 * quad + r;
        outb[(size_t)row * HH + 16 * nt + l16] = o[nt][r] * linv[r];
      }
}

extern "C" void kernel_launch(void* const* d_in, const int* in_sizes, int n_in,
                              void* d_out, int out_size, void* d_ws, size_t ws_size,
                              hipStream_t stream) {
    const float* x  = (const float*)d_in[0];
    const float* wq = (const float*)d_in[1];
    const float* wk = (const float*)d_in[2];
    const float* wv = (const float*)d_in[3];
    float* o = (float*)d_out;

    unsigned short* wf  = (unsigned short*)((char*)d_ws + WF_OFF);
    unsigned short* wsq = (unsigned short*)((char*)d_ws + Q_OFF);
    unsigned short* wsk = (unsigned short*)((char*)d_ws + K_OFF);
    unsigned short* wsv = (unsigned short*)((char*)d_ws + VT_OFF);

    pack_w_kernel<<<(WELEMS + 255) / 256, 256, 0, stream>>>(wq, wk, wv, wf);
    qkv_kernel<<<BATCH * 4, 256, 0, stream>>>(x, wf, wsq, wsk, wsv);
    attn_kernel<<<BATCH * 4, 256, 0, stream>>>(wsq, wsk, wsv, o);
}

// Round 4
// 170.241 us; speedup vs baseline: 1.1117x; 1.1117x over previous
//
#include <hip/hip_runtime.h>

#define BATCH 256
#define TT 256
#define DD 384
#define HH 64
#define SCALE 0.125f
#define SHIFT 14.0f

typedef __attribute__((ext_vector_type(8))) short short8;
typedef __attribute__((ext_vector_type(4))) float floatx4;

#define KS_STRIDE 72    // Ks [256][72] bf16
#define QS_STRIDE 72    // Qs [256][72] bf16
#define VT_STRIDE 264   // Vt [64][264] bf16
#define PS_STRIDE 40    // per-wave P scratch [16][40]
#define WELEMS (3 * DD * HH)   // 73,728 bf16 = 147,456 B packed W

__device__ __forceinline__ unsigned short f2bf(float f) {
    unsigned int u = __float_as_uint(f);
    u += 0x7fffu + ((u >> 16) & 1u);
    return (unsigned short)(u >> 16);
}
__device__ __forceinline__ float bf2f(unsigned short u) {
    return __uint_as_float(((unsigned int)u) << 16);
}

// async 16B global->LDS DMA; lane i lands at ldst + i*16B (ldst wave-uniform).
__device__ __forceinline__ void gld_lds16(const void* g, void* ldst) {
    __builtin_amdgcn_global_load_lds(
        (__attribute__((address_space(1))) void*)(unsigned long long)g,
        (__attribute__((address_space(3))) void*)(unsigned int)(unsigned long long)ldst,
        16, 0, 0);
}

// 8 fp32 -> bf16 A-fragment
__device__ __forceinline__ short8 cvt8(float4 f0, float4 f1) {
    short8 a;
    a[0] = (short)f2bf(f0.x); a[1] = (short)f2bf(f0.y);
    a[2] = (short)f2bf(f0.z); a[3] = (short)f2bf(f0.w);
    a[4] = (short)f2bf(f1.x); a[5] = (short)f2bf(f1.y);
    a[6] = (short)f2bf(f1.z); a[7] = (short)f2bf(f1.w);
    return a;
}

// Pack W fp32 [D][H] -> fragment-major bf16: wf[((ch*3+mat)*4+nt)*512 + lane*8 + j]
// holds W[d = 32ch + 8*(lane>>4) + j][h = 16nt + (lane&15)].
__global__ void pack_w_kernel(const float* __restrict__ wq,
                              const float* __restrict__ wk,
                              const float* __restrict__ wv,
                              unsigned short* __restrict__ wf) {
    int idx = blockIdx.x * 256 + threadIdx.x;
    if (idx >= WELEMS) return;
    int j = idx & 7;
    int lane = (idx >> 3) & 63;
    int nt = (idx >> 9) & 3;
    int rem = idx >> 11;                   // ch*3 + mat
    int mat = rem % 3;
    int ch = rem / 3;
    int l16 = lane & 15, q = lane >> 4;
    int h = 16 * nt + l16;
    int d = 32 * ch + 8 * q + j;
    const float* w = (mat == 0) ? wq : (mat == 1) ? wk : wv;
    wf[idx] = f2bf(w[d * HH + h]);
}

// One block per batch. 1024 thr = 16 waves = 4 waves/SIMD (2x prior occupancy).
// __launch_bounds__(1024,4) caps VGPR at 128: per-wave state was halved to fit
// (16 rows/wave -> 48 acc regs; W frags consumed 6 at a time -> 24 regs).
__global__ __launch_bounds__(1024, 4)
void fused_kernel(const float* __restrict__ x, const unsigned short* __restrict__ wfrag,
                  float* __restrict__ out) {
    // Phase 1 uses U.w (packed W, 147,456 B); phase-2 buffers alias it
    // (128,000 B), first written AFTER the post-GEMM barrier.
    __shared__ __align__(16) union LdsU {
        unsigned short w[WELEMS];                      // 147,456 B (phase 1)
        struct {
            unsigned short q[TT * QS_STRIDE];          // 36,864 B
            unsigned short ks[TT * KS_STRIDE];         // 36,864 B
            unsigned short vt[HH * VT_STRIDE];         // 33,792 B
            unsigned short p[16][16 * PS_STRIDE];      // 20,480 B
        } s;
    } U;

    const int b = blockIdx.x;
    const int tid = threadIdx.x;
    const int wave = tid >> 6;     // 0..15
    const int lane = tid & 63;
    const int quad = lane >> 4;
    const int l16 = lane & 15;

    const float* xb = x + (size_t)b * TT * DD;

    // A-fragment source: lane(l16,quad) supplies x[16*wave + l16][32ch + 8quad + j].
    const float* xr = xb + (size_t)(16 * wave + l16) * DD + 8 * quad;

    // ---------------- Phase 1: Q,K,V = x_b @ {Wq,Wk,Wv} ----------------
    floatx4 cq[4] = {}, ck[4] = {}, cv[4] = {};

    float4 xf0A, xf1A, xf0B, xf1B;
    // chunk 0/1 x loads first: HBM stream starts under the W staging.
    xf0A = *(const float4*)(xr);       xf1A = *(const float4*)(xr + 4);
    xf0B = *(const float4*)(xr + 32);  xf1B = *(const float4*)(xr + 36);

    // Stage all packed W into LDS: 144 granules of 1KB, 9 per wave, linear.
    #pragma unroll
    for (int t = 0; t < 9; ++t) {
        int grp = wave * 9 + t;    // wave-uniform
        gld_lds16(wfrag + (size_t)grp * 512 + lane * 8, U.w + grp * 512);
    }

    __syncthreads();   // W staged (drains vmcnt; x ch0/1 also landed)

    // Per chunk: 1 A-frag, 12 B-frags consumed in 2 halves of 6 (register cap),
    // 12 MFMAs. No barriers inside the loop. 2-deep x register pipeline.
    #define GEMM_BODY(X0, X1, CH)                                                  \
        {                                                                          \
            short8 a0 = cvt8(X0, X1);                                              \
            if ((CH) + 2 < 12) {                                                   \
                X0 = *(const float4*)(xr + ((CH) + 2) * 32);                       \
                X1 = *(const float4*)(xr + ((CH) + 2) * 32 + 4);                   \
            }                                                                      \
            const unsigned short* wb = U.w + (size_t)(CH) * 12 * 512 + lane * 8;   \
            _Pragma("unroll")                                                      \
            for (int h = 0; h < 2; ++h) {                                          \
                short8 fq0 = *(const short8*)(wb + (0 * 4 + 2 * h + 0) * 512);     \
                short8 fq1 = *(const short8*)(wb + (0 * 4 + 2 * h + 1) * 512);     \
                short8 fk0 = *(const short8*)(wb + (1 * 4 + 2 * h + 0) * 512);     \
                short8 fk1 = *(const short8*)(wb + (1 * 4 + 2 * h + 1) * 512);     \
                short8 fv0 = *(const short8*)(wb + (2 * 4 + 2 * h + 0) * 512);     \
                short8 fv1 = *(const short8*)(wb + (2 * 4 + 2 * h + 1) * 512);     \
                cq[2 * h]     = __builtin_amdgcn_mfma_f32_16x16x32_bf16(a0, fq0, cq[2 * h], 0, 0, 0);     \
                cq[2 * h + 1] = __builtin_amdgcn_mfma_f32_16x16x32_bf16(a0, fq1, cq[2 * h + 1], 0, 0, 0); \
                ck[2 * h]     = __builtin_amdgcn_mfma_f32_16x16x32_bf16(a0, fk0, ck[2 * h], 0, 0, 0);     \
                ck[2 * h + 1] = __builtin_amdgcn_mfma_f32_16x16x32_bf16(a0, fk1, ck[2 * h + 1], 0, 0, 0); \
                cv[2 * h]     = __builtin_amdgcn_mfma_f32_16x16x32_bf16(a0, fv0, cv[2 * h], 0, 0, 0);     \
                cv[2 * h + 1] = __builtin_amdgcn_mfma_f32_16x16x32_bf16(a0, fv1, cv[2 * h + 1], 0, 0, 0); \
            }                                                                      \
        }

    #pragma unroll 1
    for (int t = 0; t < 6; ++t) {
        GEMM_BODY(xf0A, xf1A, 2 * t);
        GEMM_BODY(xf0B, xf1B, 2 * t + 1);
    }
    #undef GEMM_BODY

    __syncthreads();   // all W-fragment reads done before overlaying with Q/Ks/Vt/P

    // C layout: row = 16*wave + 4*quad + r, col = 16*nt + l16
    #pragma unroll
    for (int nt = 0; nt < 4; ++nt)
      #pragma unroll
      for (int r = 0; r < 4; ++r) {
          int row = 16 * wave + 4 * quad + r;
          int col = 16 * nt + l16;
          U.s.q[row * QS_STRIDE + col] = f2bf(cq[nt][r]);
          U.s.ks[row * KS_STRIDE + col] = f2bf(ck[nt][r]);
          U.s.vt[col * VT_STRIDE + row] = f2bf(cv[nt][r]);
      }

    __syncthreads();

    // ---------------- Phase 2: causal attention, fixed-shift softmax ----------------
    // One q-group per wave. Permutation balances causal work per SIMD:
    // SIMD s gets groups with chunk-steps summing to exactly 18 for every s.
    int g = wave;
    if (wave & 4) g = (wave & 8) ? (27 - wave) : (11 - wave);
    const int gr0 = 16 * g;

    floatx4 o[4] = {};
    float l_run[4] = {0.f, 0.f, 0.f, 0.f};
    unsigned short* psw = U.s.p[wave];

    short8 aq0 = *(const short8*)(U.s.q + (size_t)(gr0 + l16) * QS_STRIDE + quad * 8);
    short8 aq1 = *(const short8*)(U.s.q + (size_t)(gr0 + l16) * QS_STRIDE + 32 + quad * 8);
    const int clast = g >> 1;

    for (int c = 0; c <= clast; ++c) {
        floatx4 s[2] = {};
        #pragma unroll
        for (int ni = 0; ni < 2; ++ni) {
            const unsigned short* kbase =
                U.s.ks + (size_t)(32 * c + 16 * ni + l16) * KS_STRIDE + quad * 8;
            s[ni] = __builtin_amdgcn_mfma_f32_16x16x32_bf16(aq0, *(const short8*)(kbase), s[ni], 0, 0, 0);
            s[ni] = __builtin_amdgcn_mfma_f32_16x16x32_bf16(aq1, *(const short8*)(kbase + 32), s[ni], 0, 0, 0);
        }
        bool partial = (c == clast);
        #pragma unroll
        for (int r = 0; r < 4; ++r) {
            int row = gr0 + 4 * quad + r;
            float p0 = __expf(s[0][r] * SCALE - SHIFT);
            float p1 = __expf(s[1][r] * SCALE - SHIFT);
            if (partial) {
                if (32 * c + l16 > row) p0 = 0.f;
                if (32 * c + 16 + l16 > row) p1 = 0.f;
            }
            unsigned short b0 = f2bf(p0), b1 = f2bf(p1);
            l_run[r] += bf2f(b0) + bf2f(b1);   // consistent with bf16 P fed to PV
            psw[(4 * quad + r) * PS_STRIDE + l16] = b0;
            psw[(4 * quad + r) * PS_STRIDE + 16 + l16] = b1;
        }
        short8 ap = *(const short8*)(psw + l16 * PS_STRIDE + quad * 8);
        #pragma unroll
        for (int nt = 0; nt < 4; ++nt) {
            short8 bv = *(const short8*)(U.s.vt + (size_t)(16 * nt + l16) * VT_STRIDE + 32 * c + quad * 8);
            o[nt] = __builtin_amdgcn_mfma_f32_16x16x32_bf16(ap, bv, o[nt], 0, 0, 0);
        }
    }

    // ---------------- Epilogue: l-reduction, one reciprocal per row, store ----------------
    float* outb = out + (size_t)b * TT * HH;
    float linv[4];
    #pragma unroll
    for (int r = 0; r < 4; ++r) {
        float l = l_run[r];
        l += __shfl_xor(l, 1);
        l += __shfl_xor(l, 2);
        l += __shfl_xor(l, 4);
        l += __shfl_xor(l, 8);
        linv[r] = 1.0f / l;
    }
    #pragma unroll
    for (int nt = 0; nt < 4; ++nt)
      #pragma unroll
      for (int r = 0; r < 4; ++r) {
        int row = gr0 + 4 * quad + r;
        outb[(size_t)row * HH + 16 * nt + l16] = o[nt][r] * linv[r];
      }
}

extern "C" void kernel_launch(void* const* d_in, const int* in_sizes, int n_in,
                              void* d_out, int out_size, void* d_ws, size_t ws_size,
                              hipStream_t stream) {
    const float* x  = (const float*)d_in[0];
    const float* wq = (const float*)d_in[1];
    const float* wk = (const float*)d_in[2];
    const float* wv = (const float*)d_in[3];
    unsigned short* wf = (unsigned short*)d_ws;   // fragment-major W, 147,456 B
    float* o = (float*)d_out;

    pack_w_kernel<<<(WELEMS + 255) / 256, 256, 0, stream>>>(wq, wk, wv, wf);
    fused_kernel<<<BATCH, 1024, 0, stream>>>(x, wf, o);
}